// Round 1
// baseline (1355.879 us; speedup 1.0000x reference)
//
#include <hip/hip_runtime.h>
#include <cstddef>

#define HW 192
#define NP 36864          // H*W
#define CH 256
#define EDGES 294912
#define KSIG 289
#define SLOPE 0.01f
#define BNEPS 1e-5f

__device__ __forceinline__ float leaky(float x) { return x >= 0.f ? x : SLOPE * x; }

// ---------------- generic 32x32 tiled transpose: src (R x S) -> dst (S x R) ----
__global__ __launch_bounds__(256) void k_transpose(const float* __restrict__ src,
                                                   float* __restrict__ dst, int R, int S) {
  __shared__ float tile[32][33];
  int s0 = blockIdx.x * 32, r0 = blockIdx.y * 32;
  int tx = threadIdx.x & 31, ty = threadIdx.x >> 5;
#pragma unroll
  for (int j = 0; j < 4; j++) {
    int r = r0 + ty + 8 * j;
    tile[ty + 8 * j][tx] = src[(size_t)r * S + s0 + tx];
  }
  __syncthreads();
#pragma unroll
  for (int j = 0; j < 4; j++) {
    int s = s0 + ty + 8 * j;
    dst[(size_t)s * R + r0 + tx] = tile[tx][ty + 8 * j];
  }
}

// ---------------- depthwise 17x17 conv, pad 8, leaky on input ------------------
__global__ __launch_bounds__(256) void k_dwconv17(const float* __restrict__ in,
                                                  const float* __restrict__ w,
                                                  float* __restrict__ out) {
  int c = blockIdx.y;
  int tile = blockIdx.x;
  int ty0 = (tile / 6) * 32, tx0 = (tile % 6) * 32;
  __shared__ __align__(16) float sm[48 * 48];
  const float* inc = in + (size_t)c * NP;
  for (int i = threadIdx.x; i < 48 * 48; i += 256) {
    int r = i / 48, cc = i - r * 48;
    int gy = ty0 + r - 8, gx = tx0 + cc - 8;
    float v = 0.f;
    if (gy >= 0 && gy < HW && gx >= 0 && gx < HW) v = leaky(inc[gy * HW + gx]);
    sm[i] = v;
  }
  __syncthreads();
  int r = threadIdx.x >> 3;          // 0..31 output row
  int c4 = (threadIdx.x & 7) * 4;    // output col group
  float a0 = 0.f, a1 = 0.f, a2 = 0.f, a3 = 0.f;
  const float* wc = w + c * (17 * 17);
  for (int ky = 0; ky < 17; ky++) {
    const float* rowp = &sm[(r + ky) * 48 + c4];
    float win[20];
#pragma unroll
    for (int i = 0; i < 5; i++) {
      float4 v = *(const float4*)(rowp + 4 * i);
      win[4 * i] = v.x; win[4 * i + 1] = v.y; win[4 * i + 2] = v.z; win[4 * i + 3] = v.w;
    }
#pragma unroll
    for (int kx = 0; kx < 17; kx++) {
      float wv = wc[ky * 17 + kx];
      a0 = fmaf(wv, win[kx], a0);
      a1 = fmaf(wv, win[kx + 1], a1);
      a2 = fmaf(wv, win[kx + 2], a2);
      a3 = fmaf(wv, win[kx + 3], a3);
    }
  }
  float4 o = {a0, a1, a2, a3};
  *(float4*)(out + (size_t)c * NP + (ty0 + r) * HW + tx0 + c4) = o;
}

// ---------------- grouped 3x3 conv: input channel c -> out channels 4c..4c+3 ----
__global__ __launch_bounds__(256) void k_conv3x4(const float* __restrict__ in,
                                                 const float* __restrict__ w,
                                                 float* __restrict__ out) {
  int c = blockIdx.y;
  int tile = blockIdx.x;
  int ty0 = (tile / 6) * 32, tx0 = (tile % 6) * 32;
  __shared__ __align__(16) float sm[34 * 36];
  const float* inc = in + (size_t)c * NP;
  for (int i = threadIdx.x; i < 34 * 34; i += 256) {
    int r = i / 34, cc = i - r * 34;
    int gy = ty0 + r - 1, gx = tx0 + cc - 1;
    float v = 0.f;
    if (gy >= 0 && gy < HW && gx >= 0 && gx < HW) v = leaky(inc[gy * HW + gx]);
    sm[r * 36 + cc] = v;
  }
  float wr[4][9];
#pragma unroll
  for (int oc = 0; oc < 4; oc++)
#pragma unroll
    for (int k = 0; k < 9; k++) wr[oc][k] = w[(size_t)(4 * c + oc) * 9 + k];
  __syncthreads();
  int r = threadIdx.x >> 3;
  int c4 = (threadIdx.x & 7) * 4;
  float acc[4][4];
#pragma unroll
  for (int oc = 0; oc < 4; oc++)
#pragma unroll
    for (int j = 0; j < 4; j++) acc[oc][j] = 0.f;
  for (int ky = 0; ky < 3; ky++) {
    int base = (r + ky) * 36 + c4;
    float win[6];
    float4 v4 = *(const float4*)&sm[base];
    win[0] = v4.x; win[1] = v4.y; win[2] = v4.z; win[3] = v4.w;
    win[4] = sm[base + 4]; win[5] = sm[base + 5];
#pragma unroll
    for (int oc = 0; oc < 4; oc++)
#pragma unroll
      for (int kx = 0; kx < 3; kx++) {
        float wv = wr[oc][ky * 3 + kx];
#pragma unroll
        for (int j = 0; j < 4; j++) acc[oc][j] = fmaf(wv, win[kx + j], acc[oc][j]);
      }
  }
#pragma unroll
  for (int oc = 0; oc < 4; oc++) {
    float4 o = {acc[oc][0], acc[oc][1], acc[oc][2], acc[oc][3]};
    *(float4*)(out + (size_t)(4 * c + oc) * NP + (ty0 + r) * HW + tx0 + c4) = o;
  }
}

// ---------------- GEMM: Out(M x NP) = W(M x Kd) @ f(In(Kd x NP)) + bias --------
// mode 0: f=x   mode 1: f=leaky(x)   mode 2: f=leaky(x*isc[k]+ish[k])
__global__ __launch_bounds__(256) void k_gemm(const float* __restrict__ W,
                                              const float* __restrict__ In,
                                              float* __restrict__ Out,
                                              const float* __restrict__ isc,
                                              const float* __restrict__ ish,
                                              const float* __restrict__ bias,
                                              int M, int Kd, int mode, int actout) {
  __shared__ float Ws[16][64];
  __shared__ float Is[16][64];
  int m0 = blockIdx.y * 64, n0 = blockIdx.x * 64;
  int t = threadIdx.x;
  int tx = t & 15, ty = t >> 4;
  int lm = t >> 2;           // 0..63  W row in tile
  int lk4 = (t & 3) * 4;     // k offset for W load
  int lik = t >> 4;          // 0..15  In k row
  int lin = (t & 15) * 4;    // In col offset
  float acc[4][4];
#pragma unroll
  for (int i = 0; i < 4; i++)
#pragma unroll
    for (int j = 0; j < 4; j++) acc[i][j] = 0.f;

  for (int k0 = 0; k0 < Kd; k0 += 16) {
    float4 wv = {0.f, 0.f, 0.f, 0.f};
    int gm = m0 + lm;
    if (gm < M) wv = *(const float4*)(W + (size_t)gm * Kd + k0 + lk4);
    Ws[lk4 + 0][lm] = wv.x; Ws[lk4 + 1][lm] = wv.y;
    Ws[lk4 + 2][lm] = wv.z; Ws[lk4 + 3][lm] = wv.w;

    int gk = k0 + lik;
    float4 iv = *(const float4*)(In + (size_t)gk * NP + n0 + lin);
    if (mode == 2) {
      float s = isc[gk], h = ish[gk];
      iv.x = leaky(fmaf(iv.x, s, h)); iv.y = leaky(fmaf(iv.y, s, h));
      iv.z = leaky(fmaf(iv.z, s, h)); iv.w = leaky(fmaf(iv.w, s, h));
    } else if (mode == 1) {
      iv.x = leaky(iv.x); iv.y = leaky(iv.y); iv.z = leaky(iv.z); iv.w = leaky(iv.w);
    }
    *(float4*)&Is[lik][lin] = iv;
    __syncthreads();
#pragma unroll
    for (int kk = 0; kk < 16; kk++) {
      float4 a = *(const float4*)&Ws[kk][ty * 4];
      float4 b = *(const float4*)&Is[kk][tx * 4];
      float av[4] = {a.x, a.y, a.z, a.w};
      float bv[4] = {b.x, b.y, b.z, b.w};
#pragma unroll
      for (int i = 0; i < 4; i++)
#pragma unroll
        for (int j = 0; j < 4; j++) acc[i][j] = fmaf(av[i], bv[j], acc[i][j]);
    }
    __syncthreads();
  }
#pragma unroll
  for (int i = 0; i < 4; i++) {
    int m = m0 + ty * 4 + i;
    if (m >= M) continue;
    float bs = bias ? bias[m] : 0.f;
    float4 o = {acc[i][0] + bs, acc[i][1] + bs, acc[i][2] + bs, acc[i][3] + bs};
    if (actout) { o.x = leaky(o.x); o.y = leaky(o.y); o.z = leaky(o.z); o.w = leaky(o.w); }
    *(float4*)(Out + (size_t)m * NP + n0 + tx * 4) = o;
  }
}

// ---------------- per-row (channel) BN stats -> scale/shift --------------------
__global__ __launch_bounds__(256) void k_rowstats(const float* __restrict__ Xr,
                                                  const float* __restrict__ g,
                                                  const float* __restrict__ b,
                                                  float* __restrict__ scale,
                                                  float* __restrict__ shift) {
  int row = blockIdx.x;
  int t = threadIdx.x;
  const float4* p = (const float4*)(Xr + (size_t)row * NP);
  float s = 0.f, q = 0.f;
  for (int i = t; i < NP / 4; i += 256) {
    float4 v = p[i];
    s += v.x + v.y + v.z + v.w;
    q += v.x * v.x + v.y * v.y + v.z * v.z + v.w * v.w;
  }
  __shared__ float ss[256], qq[256];
  ss[t] = s; qq[t] = q;
  __syncthreads();
  for (int d = 128; d > 0; d >>= 1) {
    if (t < d) { ss[t] += ss[t + d]; qq[t] += qq[t + d]; }
    __syncthreads();
  }
  if (t == 0) {
    float mean = ss[0] * (1.f / NP);
    float var = qq[0] * (1.f / NP) - mean * mean;
    float iv = rsqrtf(var + BNEPS);
    float scl = g[row] * iv;
    scale[row] = scl;
    shift[row] = b[row] - mean * scl;
  }
}

// ---------------- dst = base + raw*sc[c]+sh[c]  (channel-major) ----------------
__global__ __launch_bounds__(256) void k_addbn(const float* __restrict__ base,
                                               const float* __restrict__ raw,
                                               const float* __restrict__ sc,
                                               const float* __restrict__ sh,
                                               float* __restrict__ dst) {
  size_t i = (size_t)blockIdx.x * 256 + threadIdx.x;
  int c = (int)((i * 4) / NP);
  float s = sc[c], h = sh[c];
  float4 b4 = ((const float4*)base)[i];
  float4 r4 = ((const float4*)raw)[i];
  float4 o;
  o.x = b4.x + fmaf(r4.x, s, h); o.y = b4.y + fmaf(r4.y, s, h);
  o.z = b4.z + fmaf(r4.z, s, h); o.w = b4.w + fmaf(r4.w, s, h);
  ((float4*)dst)[i] = o;
}

// ---------------- edge scores + dst histogram ----------------------------------
__global__ __launch_bounds__(256) void k_edge(const int* __restrict__ info,
                                              const float* __restrict__ msk,
                                              const float* __restrict__ sig,
                                              float* __restrict__ aij,
                                              int* __restrict__ counts) {
  int e = blockIdx.x * 256 + threadIdx.x;
  int4 ii = ((const int4*)info)[e];   // src, k1, dst, k2
  float s = sig[(size_t)ii.y * NP + ii.x] + sig[(size_t)ii.w * NP + ii.z];
  s = fminf(fmaxf(s, -5.f), 5.f);
  aij[e] = expf(s) * msk[e];
  atomicAdd(&counts[ii.z], 1);
}

// ---------------- counting-sort by dst: 3-kernel scan + scatter ----------------
__global__ __launch_bounds__(256) void k_scan1(const int* __restrict__ counts,
                                               int* __restrict__ offsets,
                                               int* __restrict__ bsum) {
  __shared__ int sm[256];
  int t = threadIdx.x;
  int i = blockIdx.x * 256 + t;
  int v = counts[i];
  sm[t] = v;
  __syncthreads();
  for (int d = 1; d < 256; d <<= 1) {
    int add = (t >= d) ? sm[t - d] : 0;
    __syncthreads();
    sm[t] += add;
    __syncthreads();
  }
  offsets[i] = sm[t] - v;
  if (t == 255) bsum[blockIdx.x] = sm[255];
}
__global__ __launch_bounds__(256) void k_scan2(const int* __restrict__ bsum,
                                               int* __restrict__ boff) {
  __shared__ int sm[256];
  int t = threadIdx.x;
  int v = (t < 144) ? bsum[t] : 0;
  sm[t] = v;
  __syncthreads();
  for (int d = 1; d < 256; d <<= 1) {
    int add = (t >= d) ? sm[t - d] : 0;
    __syncthreads();
    sm[t] += add;
    __syncthreads();
  }
  boff[t] = sm[t] - v;
}
__global__ __launch_bounds__(256) void k_scan3(int* __restrict__ offsets,
                                               const int* __restrict__ boff,
                                               int* __restrict__ cursor) {
  int i = blockIdx.x * 256 + threadIdx.x;
  int o = offsets[i] + boff[blockIdx.x];
  offsets[i] = o;
  cursor[i] = o;
  if (i == 0) offsets[NP] = EDGES;
}
__global__ __launch_bounds__(256) void k_scatter(const int* __restrict__ info,
                                                 int* __restrict__ cursor,
                                                 int* __restrict__ sorted) {
  int e = blockIdx.x * 256 + threadIdx.x;
  int d = info[4 * e + 2];
  int pos = atomicAdd(&cursor[d], 1);
  sorted[pos] = e;
}

// ---------------- per-node aggregation (one wave per node) ---------------------
__global__ __launch_bounds__(256) void k_agg(const int* __restrict__ offsets,
                                             const int* __restrict__ sorted,
                                             const float* __restrict__ aij,
                                             const int* __restrict__ info,
                                             const float* __restrict__ Xn,
                                             float* __restrict__ Xtr) {
  int wave = threadIdx.x >> 6, lane = threadIdx.x & 63;
  int node = blockIdx.x * 4 + wave;
  int o0 = offsets[node], o1 = offsets[node + 1];
  float ax = 0.f, ay = 0.f, az = 0.f, aw = 0.f, asum = 0.f;
  for (int i = o0; i < o1; i++) {
    int e = sorted[i];
    float a = aij[e];
    int s = info[4 * e];
    float4 v = ((const float4*)(Xn + (size_t)s * CH))[lane];
    ax = fmaf(a, v.x, ax); ay = fmaf(a, v.y, ay);
    az = fmaf(a, v.z, az); aw = fmaf(a, v.w, aw);
    asum += a;
  }
  float inv = 1.f / (asum + 1e-5f);
  float4 o = {ax * inv, ay * inv, az * inv, aw * inv};
  ((float4*)(Xtr + (size_t)node * CH))[lane] = o;
}

// ---------------- bn1d stats (node-major input) --------------------------------
__global__ __launch_bounds__(256) void k_colstats(const float* __restrict__ Xt,
                                                  float* __restrict__ sums,
                                                  float* __restrict__ sqs) {
  int c = threadIdx.x;
  float s = 0.f, q = 0.f;
  for (int n = blockIdx.x; n < NP; n += gridDim.x) {
    float v = Xt[(size_t)n * CH + c];
    s += v; q += v * v;
  }
  atomicAdd(&sums[c], s);
  atomicAdd(&sqs[c], q);
}
__global__ __launch_bounds__(256) void k_bn1dfin(const float* __restrict__ sums,
                                                 const float* __restrict__ sqs,
                                                 const float* __restrict__ g,
                                                 const float* __restrict__ b,
                                                 float* __restrict__ sct,
                                                 float* __restrict__ sht) {
  int c = threadIdx.x;
  float mean = sums[c] * (1.f / NP);
  float var = sqs[c] * (1.f / NP) - mean * mean;
  float iv = rsqrtf(var + BNEPS);
  float scl = g[c] * iv;
  sct[c] = scl;
  sht[c] = b[c] - mean * scl;
}

// ---------------- img4 = transpose(Xn + Xtr*sct+sht)  (N x C -> C x N) ---------
__global__ __launch_bounds__(256) void k_mkimg4(const float* __restrict__ Xn,
                                                const float* __restrict__ Xtr,
                                                const float* __restrict__ sct,
                                                const float* __restrict__ sht,
                                                float* __restrict__ img4) {
  __shared__ float tile[32][33];
  int c0 = blockIdx.x * 32, n0 = blockIdx.y * 32;
  int tx = threadIdx.x & 31, ty = threadIdx.x >> 5;
  int c = c0 + tx;
  float s = sct[c], h = sht[c];
#pragma unroll
  for (int j = 0; j < 4; j++) {
    size_t idx = (size_t)(n0 + ty + 8 * j) * CH + c;
    tile[ty + 8 * j][tx] = Xn[idx] + fmaf(Xtr[idx], s, h);
  }
  __syncthreads();
#pragma unroll
  for (int j = 0; j < 4; j++) {
    int cc = c0 + ty + 8 * j;
    img4[(size_t)cc * NP + n0 + tx] = tile[tx][ty + 8 * j];
  }
}

// ---------------- out(N x C) = transpose(raw5*sc5+sh5 + img4) ------------------
__global__ __launch_bounds__(256) void k_final(const float* __restrict__ raw5,
                                               const float* __restrict__ img4,
                                               const float* __restrict__ sc5,
                                               const float* __restrict__ sh5,
                                               float* __restrict__ out) {
  __shared__ float tile[32][33];
  int n0 = blockIdx.x * 32, c0 = blockIdx.y * 32;
  int tx = threadIdx.x & 31, ty = threadIdx.x >> 5;
#pragma unroll
  for (int j = 0; j < 4; j++) {
    int c = c0 + ty + 8 * j;
    size_t idx = (size_t)c * NP + n0 + tx;
    tile[ty + 8 * j][tx] = fmaf(raw5[idx], sc5[c], sh5[c]) + img4[idx];
  }
  __syncthreads();
#pragma unroll
  for (int j = 0; j < 4; j++) {
    int n = n0 + ty + 8 * j;
    out[(size_t)n * CH + c0 + tx] = tile[tx][ty + 8 * j];
  }
}

extern "C" void kernel_launch(void* const* d_in, const int* in_sizes, int n_in,
                              void* d_out, int out_size, void* d_ws, size_t ws_size,
                              hipStream_t stream) {
  (void)in_sizes; (void)n_in; (void)out_size; (void)ws_size;
  const float* X    = (const float*)d_in[0];
  const int*   info = (const int*)d_in[1];
  const float* msk  = (const float*)d_in[2];
  const float* pw0  = (const float*)d_in[3];
  const float* pg0  = (const float*)d_in[4];
  const float* pb0  = (const float*)d_in[5];
  const float* pw1  = (const float*)d_in[6];
  const float* pg1  = (const float*)d_in[7];
  const float* pb1  = (const float*)d_in[8];
  const float* f1w0 = (const float*)d_in[9];
  const float* f1g0 = (const float*)d_in[10];
  const float* f1b0 = (const float*)d_in[11];
  const float* f1w1 = (const float*)d_in[12];
  const float* f1g1 = (const float*)d_in[13];
  const float* f1b1 = (const float*)d_in[14];
  const float* dw1  = (const float*)d_in[15];
  const float* db1  = (const float*)d_in[16];
  const float* dw2  = (const float*)d_in[17];
  const float* db2  = (const float*)d_in[18];
  const float* bng  = (const float*)d_in[19];
  const float* bnb  = (const float*)d_in[20];
  const float* f2w0 = (const float*)d_in[21];
  const float* f2g0 = (const float*)d_in[22];
  const float* f2b0 = (const float*)d_in[23];
  const float* f2w1 = (const float*)d_in[24];
  const float* f2g1 = (const float*)d_in[25];
  const float* f2b1 = (const float*)d_in[26];
  float* out = (float*)d_out;

  // workspace layout (4-byte words); total 66,781,184 words ~= 255 MiB
  float* ws = (float*)d_ws;
  float* sc0 = ws + 0;    float* sh0 = ws + 256;
  float* sc1 = ws + 512;  float* sh1 = ws + 768;
  float* sc2 = ws + 1024; float* sh2 = ws + 1280;
  float* sc3 = ws + 1536; float* sh3 = ws + 1792;
  float* sc4 = ws + 2048; float* sh4 = ws + 3072;  // 1024 each
  float* sc5 = ws + 4096; float* sh5 = ws + 4352;
  float* sct = ws + 4608; float* sht = ws + 4864;
  float* sums = ws + 5120; float* sqs = ws + 5376;
  int* counts  = (int*)(ws + 8192);     // NP
  int* offsets = (int*)(ws + 45056);    // NP+1
  int* cursor  = (int*)(ws + 82176);    // NP+1
  int* bsum    = (int*)(ws + 119296);   // 144
  int* boff    = (int*)(ws + 119552);   // 256
  int* sorted  = (int*)(ws + 131072);   // EDGES
  float* aij   = ws + 425984;           // EDGES
  float* slotB = ws + 720896;                       // raw0 / raw2 / hT / raw5
  float* slotC = slotB + (size_t)NP * CH;           // raw1 / raw3 / Xn
  float* slotD = slotC + (size_t)NP * CH;           // img2 / img4
  float* slotA = slotD + (size_t)NP * CH;           // img / img3 / X_trans
  float* sigT  = slotA + (size_t)NP * CH;           // K x N signal
  float* raw4  = slotA;  // 4C x N, overlaps A+sigT+extra (all dead by then)

  hipMemsetAsync(counts, 0, NP * sizeof(int), stream);
  hipMemsetAsync(sums, 0, 512 * sizeof(float), stream);

  dim3 b256(256);
  // img = X^T
  k_transpose<<<dim3(CH / 32, NP / 32), b256, 0, stream>>>(X, slotA, NP, CH);
  // ppm depthwise 17x17
  k_dwconv17<<<dim3(36, CH), b256, 0, stream>>>(slotA, pw0, slotB);
  k_rowstats<<<CH, b256, 0, stream>>>(slotB, pg0, pb0, sc0, sh0);
  // ppm 1x1
  k_gemm<<<dim3(NP / 64, CH / 64), b256, 0, stream>>>(pw1, slotB, slotC, sc0, sh0, nullptr, CH, CH, 2, 0);
  k_rowstats<<<CH, b256, 0, stream>>>(slotC, pg1, pb1, sc1, sh1);
  k_addbn<<<NP * CH / 1024, b256, 0, stream>>>(slotA, slotC, sc1, sh1, slotD); // img2
  // ffn1
  k_gemm<<<dim3(NP / 64, CH / 64), b256, 0, stream>>>(f1w0, slotD, slotB, nullptr, nullptr, nullptr, CH, CH, 1, 0);
  k_rowstats<<<CH, b256, 0, stream>>>(slotB, f1g0, f1b0, sc2, sh2);
  k_gemm<<<dim3(NP / 64, CH / 64), b256, 0, stream>>>(f1w1, slotB, slotC, sc2, sh2, nullptr, CH, CH, 2, 0);
  k_rowstats<<<CH, b256, 0, stream>>>(slotC, f1g1, f1b1, sc3, sh3);
  k_addbn<<<NP * CH / 1024, b256, 0, stream>>>(slotD, slotC, sc3, sh3, slotA); // img3
  // Xn = img3^T (node-major)
  k_transpose<<<dim3(NP / 32, CH / 32), b256, 0, stream>>>(slotA, slotC, CH, NP);
  // dis
  k_gemm<<<dim3(NP / 64, CH / 64), b256, 0, stream>>>(dw1, slotA, slotB, nullptr, nullptr, db1, CH, CH, 0, 1);
  k_gemm<<<dim3(NP / 64, 5), b256, 0, stream>>>(dw2, slotB, sigT, nullptr, nullptr, db2, KSIG, CH, 0, 0);
  // edges
  k_edge<<<EDGES / 256, b256, 0, stream>>>(info, msk, sigT, aij, counts);
  k_scan1<<<NP / 256, b256, 0, stream>>>(counts, offsets, bsum);
  k_scan2<<<1, b256, 0, stream>>>(bsum, boff);
  k_scan3<<<NP / 256, b256, 0, stream>>>(offsets, boff, cursor);
  k_scatter<<<EDGES / 256, b256, 0, stream>>>(info, cursor, sorted);
  k_agg<<<NP / 4, b256, 0, stream>>>(offsets, sorted, aij, info, slotC, slotA); // X_trans
  k_colstats<<<288, b256, 0, stream>>>(slotA, sums, sqs);
  k_bn1dfin<<<1, b256, 0, stream>>>(sums, sqs, bng, bnb, sct, sht);
  k_mkimg4<<<dim3(CH / 32, NP / 32), b256, 0, stream>>>(slotC, slotA, sct, sht, slotD); // img4
  // ffn2
  k_conv3x4<<<dim3(36, CH), b256, 0, stream>>>(slotD, f2w0, raw4);
  k_rowstats<<<4 * CH, b256, 0, stream>>>(raw4, f2g0, f2b0, sc4, sh4);
  k_gemm<<<dim3(NP / 64, CH / 64), b256, 0, stream>>>(f2w1, raw4, slotB, sc4, sh4, nullptr, CH, 4 * CH, 2, 0);
  k_rowstats<<<CH, b256, 0, stream>>>(slotB, f2g1, f2b1, sc5, sh5);
  k_final<<<dim3(NP / 32, CH / 32), b256, 0, stream>>>(slotB, slotD, sc5, sh5, out);
}

// Round 2
// 863.220 us; speedup vs baseline: 1.5707x; 1.5707x over previous
//
#include <hip/hip_runtime.h>
#include <cstddef>

#define HW 192
#define NP 36864          // H*W
#define CH 256
#define EDGES 294912
#define KSIG 289
#define SLOPE 0.01f
#define BNEPS 1e-5f

typedef unsigned short u16;
typedef __attribute__((ext_vector_type(8))) short bf16x8;
typedef __attribute__((ext_vector_type(4))) float f32x4;

__device__ __forceinline__ float leaky(float x) { return x >= 0.f ? x : SLOPE * x; }
__device__ __forceinline__ u16 f2bf(float x) {
  unsigned u = __float_as_uint(x);
  unsigned r = (u + 0x7fffu + ((u >> 16) & 1u)) >> 16;
  return (u16)r;
}
__device__ __forceinline__ float bf2f(unsigned h) { return __uint_as_float(h << 16); }

// ---------------- generic 32x32 tiled transpose: src (R x S) -> dst (S x R) ----
__global__ __launch_bounds__(256) void k_transpose(const float* __restrict__ src,
                                                   float* __restrict__ dst, int R, int S) {
  __shared__ float tile[32][33];
  int s0 = blockIdx.x * 32, r0 = blockIdx.y * 32;
  int tx = threadIdx.x & 31, ty = threadIdx.x >> 5;
#pragma unroll
  for (int j = 0; j < 4; j++) {
    int r = r0 + ty + 8 * j;
    tile[ty + 8 * j][tx] = src[(size_t)r * S + s0 + tx];
  }
  __syncthreads();
#pragma unroll
  for (int j = 0; j < 4; j++) {
    int s = s0 + ty + 8 * j;
    dst[(size_t)s * R + r0 + tx] = tile[tx][ty + 8 * j];
  }
}

// ---------------- weight fp32 -> bf16 converter (dw2 zero-padded to 384 rows) --
__global__ __launch_bounds__(256) void k_cvtW(const float* __restrict__ pw1,
                                              const float* __restrict__ f1w0,
                                              const float* __restrict__ f1w1,
                                              const float* __restrict__ dw1,
                                              const float* __restrict__ dw2,
                                              const float* __restrict__ f2w1,
                                              u16* __restrict__ out) {
  int i = blockIdx.x * 256 + threadIdx.x;   // 0..622591
  float v;
  if (i < 65536) v = pw1[i];
  else if (i < 131072) v = f1w0[i - 65536];
  else if (i < 196608) v = f1w1[i - 131072];
  else if (i < 262144) v = dw1[i - 196608];
  else if (i < 360448) { int j = i - 262144; v = (j < KSIG * 256) ? dw2[j] : 0.f; }
  else v = f2w1[i - 360448];
  out[i] = f2bf(v);
}

// ---- fp32 (M x NP) -> bf16 transposed (NP x M), transform fused at load -------
// mode 0: x   mode 1: leaky(x)   mode 2: leaky(x*sc[k]+sh[k])
__global__ __launch_bounds__(256) void k_cvtT(const float* __restrict__ in,
                                              u16* __restrict__ outT,
                                              const float* __restrict__ sc,
                                              const float* __restrict__ sh,
                                              int M, int mode) {
  __shared__ float tile[32][65];
  int n0 = blockIdx.x * 64, k0 = blockIdx.y * 32;
  int t = threadIdx.x;
#pragma unroll
  for (int i = 0; i < 2; i++) {
    int ci = i * 256 + t;
    int k = ci >> 4, cg = (ci & 15) * 4;
    float s = 1.f, h = 0.f;
    if (mode == 2) { s = sc[k0 + k]; h = sh[k0 + k]; }
    float4 v = *(const float4*)&in[(size_t)(k0 + k) * NP + n0 + cg];
    if (mode == 2) {
      v.x = leaky(fmaf(v.x, s, h)); v.y = leaky(fmaf(v.y, s, h));
      v.z = leaky(fmaf(v.z, s, h)); v.w = leaky(fmaf(v.w, s, h));
    } else if (mode == 1) {
      v.x = leaky(v.x); v.y = leaky(v.y); v.z = leaky(v.z); v.w = leaky(v.w);
    }
    tile[k][cg] = v.x; tile[k][cg + 1] = v.y; tile[k][cg + 2] = v.z; tile[k][cg + 3] = v.w;
  }
  __syncthreads();
  int n = t >> 2, kg = (t & 3) * 8;
  uint4 o;
  o.x = (unsigned)f2bf(tile[kg + 0][n]) | ((unsigned)f2bf(tile[kg + 1][n]) << 16);
  o.y = (unsigned)f2bf(tile[kg + 2][n]) | ((unsigned)f2bf(tile[kg + 3][n]) << 16);
  o.z = (unsigned)f2bf(tile[kg + 4][n]) | ((unsigned)f2bf(tile[kg + 5][n]) << 16);
  o.w = (unsigned)f2bf(tile[kg + 6][n]) | ((unsigned)f2bf(tile[kg + 7][n]) << 16);
  *(uint4*)&outT[(size_t)(n0 + n) * M + k0 + kg] = o;
}

// ---- bf16 (M x NP) -> bf16 transposed (NP x M), mode2 transform ---------------
__global__ __launch_bounds__(256) void k_cvtT_bf(const u16* __restrict__ in,
                                                 u16* __restrict__ outT,
                                                 const float* __restrict__ sc,
                                                 const float* __restrict__ sh,
                                                 int M) {
  __shared__ float tile[32][65];
  int n0 = blockIdx.x * 64, k0 = blockIdx.y * 32;
  int t = threadIdx.x;
  int k = t >> 3, cg = (t & 7) * 8;
  float s = sc[k0 + k], h = sh[k0 + k];
  uint4 v = *(const uint4*)&in[(size_t)(k0 + k) * NP + n0 + cg];
  unsigned w[4] = {v.x, v.y, v.z, v.w};
#pragma unroll
  for (int j = 0; j < 4; j++) {
    tile[k][cg + 2 * j]     = leaky(fmaf(bf2f(w[j] & 0xffffu), s, h));
    tile[k][cg + 2 * j + 1] = leaky(fmaf(bf2f(w[j] >> 16), s, h));
  }
  __syncthreads();
  int n = t >> 2, kg = (t & 3) * 8;
  uint4 o;
  o.x = (unsigned)f2bf(tile[kg + 0][n]) | ((unsigned)f2bf(tile[kg + 1][n]) << 16);
  o.y = (unsigned)f2bf(tile[kg + 2][n]) | ((unsigned)f2bf(tile[kg + 3][n]) << 16);
  o.z = (unsigned)f2bf(tile[kg + 4][n]) | ((unsigned)f2bf(tile[kg + 5][n]) << 16);
  o.w = (unsigned)f2bf(tile[kg + 6][n]) | ((unsigned)f2bf(tile[kg + 7][n]) << 16);
  *(uint4*)&outT[(size_t)(n0 + n) * M + k0 + kg] = o;
}

// ---------------- MFMA GEMM: Out(Mstore x NP) = A(Mt x K) @ Bt(NP x K)^T -------
// A: bf16 M x K row-major.  Bt: bf16 NP x K row-major (i.e. B transposed).
__global__ __launch_bounds__(256) void k_mgemm(const u16* __restrict__ A,
                                               const u16* __restrict__ Bt,
                                               float* __restrict__ Out,
                                               const float* __restrict__ bias,
                                               int K, int Mstore, int actout) {
  __shared__ u16 As[128 * 32];
  __shared__ u16 Bs[128 * 32];
  int t = threadIdx.x;
  int lane = t & 63, wave = t >> 6;
  int wm = (wave >> 1) * 64, wn = (wave & 1) * 64;
  int m0 = blockIdx.y * 128, n0 = blockIdx.x * 128;
  int r = lane & 15, q = lane >> 4;
  f32x4 acc[4][4];
#pragma unroll
  for (int a = 0; a < 4; a++)
#pragma unroll
    for (int b = 0; b < 4; b++) acc[a][b] = (f32x4){0.f, 0.f, 0.f, 0.f};

  for (int k0 = 0; k0 < K; k0 += 32) {
#pragma unroll
    for (int i = 0; i < 2; i++) {
      int cc = t + i * 256;            // chunk 0..511
      int mm = cc >> 2, kq = (cc & 3) * 8;
      uint4 av = *(const uint4*)&A[(size_t)(m0 + mm) * K + k0 + kq];
      uint4 bv = *(const uint4*)&Bt[(size_t)(n0 + mm) * K + k0 + kq];
      *(uint4*)&As[mm * 32 + kq] = av;
      *(uint4*)&Bs[mm * 32 + kq] = bv;
    }
    __syncthreads();
    bf16x8 af[4], bfr[4];
#pragma unroll
    for (int mt = 0; mt < 4; mt++)
      af[mt] = *(const bf16x8*)&As[(wm + mt * 16 + r) * 32 + q * 8];
#pragma unroll
    for (int nt = 0; nt < 4; nt++)
      bfr[nt] = *(const bf16x8*)&Bs[(wn + nt * 16 + r) * 32 + q * 8];
#pragma unroll
    for (int mt = 0; mt < 4; mt++)
#pragma unroll
      for (int nt = 0; nt < 4; nt++)
        acc[mt][nt] = __builtin_amdgcn_mfma_f32_16x16x32_bf16(af[mt], bfr[nt], acc[mt][nt], 0, 0, 0);
    __syncthreads();
  }
#pragma unroll
  for (int mt = 0; mt < 4; mt++) {
    int mrow = m0 + wm + mt * 16 + q * 4;
#pragma unroll
    for (int i = 0; i < 4; i++) {
      int m = mrow + i;
      if (m >= Mstore) continue;
      float bs = bias ? bias[m] : 0.f;
#pragma unroll
      for (int nt = 0; nt < 4; nt++) {
        float v = acc[mt][nt][i] + bs;
        if (actout) v = leaky(v);
        Out[(size_t)m * NP + n0 + wn + nt * 16 + r] = v;
      }
    }
  }
}

// ---------------- depthwise 17x17 conv, pad 8, leaky on input ------------------
__global__ __launch_bounds__(256) void k_dwconv17(const float* __restrict__ in,
                                                  const float* __restrict__ w,
                                                  float* __restrict__ out) {
  int c = blockIdx.y;
  int tile = blockIdx.x;
  int ty0 = (tile / 6) * 32, tx0 = (tile % 6) * 32;
  __shared__ __align__(16) float sm[48 * 48];
  const float* inc = in + (size_t)c * NP;
  for (int i = threadIdx.x; i < 48 * 48; i += 256) {
    int r = i / 48, cc = i - r * 48;
    int gy = ty0 + r - 8, gx = tx0 + cc - 8;
    float v = 0.f;
    if (gy >= 0 && gy < HW && gx >= 0 && gx < HW) v = leaky(inc[gy * HW + gx]);
    sm[i] = v;
  }
  __syncthreads();
  int r = threadIdx.x >> 3;
  int c4 = (threadIdx.x & 7) * 4;
  float a0 = 0.f, a1 = 0.f, a2 = 0.f, a3 = 0.f;
  const float* wc = w + c * (17 * 17);
  for (int ky = 0; ky < 17; ky++) {
    const float* rowp = &sm[(r + ky) * 48 + c4];
    float win[20];
#pragma unroll
    for (int i = 0; i < 5; i++) {
      float4 v = *(const float4*)(rowp + 4 * i);
      win[4 * i] = v.x; win[4 * i + 1] = v.y; win[4 * i + 2] = v.z; win[4 * i + 3] = v.w;
    }
#pragma unroll
    for (int kx = 0; kx < 17; kx++) {
      float wv = wc[ky * 17 + kx];
      a0 = fmaf(wv, win[kx], a0);
      a1 = fmaf(wv, win[kx + 1], a1);
      a2 = fmaf(wv, win[kx + 2], a2);
      a3 = fmaf(wv, win[kx + 3], a3);
    }
  }
  float4 o = {a0, a1, a2, a3};
  *(float4*)(out + (size_t)c * NP + (ty0 + r) * HW + tx0 + c4) = o;
}

// ---------------- grouped 3x3 conv -> bf16 output ------------------------------
__global__ __launch_bounds__(256) void k_conv3x4(const float* __restrict__ in,
                                                 const float* __restrict__ w,
                                                 u16* __restrict__ out) {
  int c = blockIdx.y;
  int tile = blockIdx.x;
  int ty0 = (tile / 6) * 32, tx0 = (tile % 6) * 32;
  __shared__ __align__(16) float sm[34 * 36];
  const float* inc = in + (size_t)c * NP;
  for (int i = threadIdx.x; i < 34 * 34; i += 256) {
    int r = i / 34, cc = i - r * 34;
    int gy = ty0 + r - 1, gx = tx0 + cc - 1;
    float v = 0.f;
    if (gy >= 0 && gy < HW && gx >= 0 && gx < HW) v = leaky(inc[gy * HW + gx]);
    sm[r * 36 + cc] = v;
  }
  float wr[4][9];
#pragma unroll
  for (int oc = 0; oc < 4; oc++)
#pragma unroll
    for (int k = 0; k < 9; k++) wr[oc][k] = w[(size_t)(4 * c + oc) * 9 + k];
  __syncthreads();
  int r = threadIdx.x >> 3;
  int c4 = (threadIdx.x & 7) * 4;
  float acc[4][4];
#pragma unroll
  for (int oc = 0; oc < 4; oc++)
#pragma unroll
    for (int j = 0; j < 4; j++) acc[oc][j] = 0.f;
  for (int ky = 0; ky < 3; ky++) {
    int base = (r + ky) * 36 + c4;
    float win[6];
    float4 v4 = *(const float4*)&sm[base];
    win[0] = v4.x; win[1] = v4.y; win[2] = v4.z; win[3] = v4.w;
    win[4] = sm[base + 4]; win[5] = sm[base + 5];
#pragma unroll
    for (int oc = 0; oc < 4; oc++)
#pragma unroll
      for (int kx = 0; kx < 3; kx++) {
        float wv = wr[oc][ky * 3 + kx];
#pragma unroll
        for (int j = 0; j < 4; j++) acc[oc][j] = fmaf(wv, win[kx + j], acc[oc][j]);
      }
  }
#pragma unroll
  for (int oc = 0; oc < 4; oc++) {
    uint2 o;
    o.x = (unsigned)f2bf(acc[oc][0]) | ((unsigned)f2bf(acc[oc][1]) << 16);
    o.y = (unsigned)f2bf(acc[oc][2]) | ((unsigned)f2bf(acc[oc][3]) << 16);
    *(uint2*)(out + (size_t)(4 * c + oc) * NP + (ty0 + r) * HW + tx0 + c4) = o;
  }
}

// ---------------- per-row (channel) BN stats -> scale/shift --------------------
__global__ __launch_bounds__(256) void k_rowstats(const float* __restrict__ Xr,
                                                  const float* __restrict__ g,
                                                  const float* __restrict__ b,
                                                  float* __restrict__ scale,
                                                  float* __restrict__ shift) {
  int row = blockIdx.x;
  int t = threadIdx.x;
  const float4* p = (const float4*)(Xr + (size_t)row * NP);
  float s = 0.f, q = 0.f;
  for (int i = t; i < NP / 4; i += 256) {
    float4 v = p[i];
    s += v.x + v.y + v.z + v.w;
    q += v.x * v.x + v.y * v.y + v.z * v.z + v.w * v.w;
  }
  __shared__ float ss[256], qq[256];
  ss[t] = s; qq[t] = q;
  __syncthreads();
  for (int d = 128; d > 0; d >>= 1) {
    if (t < d) { ss[t] += ss[t + d]; qq[t] += qq[t + d]; }
    __syncthreads();
  }
  if (t == 0) {
    float mean = ss[0] * (1.f / NP);
    float var = qq[0] * (1.f / NP) - mean * mean;
    float iv = rsqrtf(var + BNEPS);
    float scl = g[row] * iv;
    scale[row] = scl;
    shift[row] = b[row] - mean * scl;
  }
}

__global__ __launch_bounds__(256) void k_rowstats_bf(const u16* __restrict__ Xr,
                                                     const float* __restrict__ g,
                                                     const float* __restrict__ b,
                                                     float* __restrict__ scale,
                                                     float* __restrict__ shift) {
  int row = blockIdx.x;
  int t = threadIdx.x;
  const uint4* p = (const uint4*)(Xr + (size_t)row * NP);
  float s = 0.f, q = 0.f;
  for (int i = t; i < NP / 8; i += 256) {
    uint4 v = p[i];
    unsigned w[4] = {v.x, v.y, v.z, v.w};
#pragma unroll
    for (int j = 0; j < 4; j++) {
      float a = bf2f(w[j] & 0xffffu), c = bf2f(w[j] >> 16);
      s += a + c; q += a * a + c * c;
    }
  }
  __shared__ float ss[256], qq[256];
  ss[t] = s; qq[t] = q;
  __syncthreads();
  for (int d = 128; d > 0; d >>= 1) {
    if (t < d) { ss[t] += ss[t + d]; qq[t] += qq[t + d]; }
    __syncthreads();
  }
  if (t == 0) {
    float mean = ss[0] * (1.f / NP);
    float var = qq[0] * (1.f / NP) - mean * mean;
    float iv = rsqrtf(var + BNEPS);
    float scl = g[row] * iv;
    scale[row] = scl;
    shift[row] = b[row] - mean * scl;
  }
}

// ---------------- dst = base + raw*sc[c]+sh[c]  (channel-major) ----------------
__global__ __launch_bounds__(256) void k_addbn(const float* __restrict__ base,
                                               const float* __restrict__ raw,
                                               const float* __restrict__ sc,
                                               const float* __restrict__ sh,
                                               float* __restrict__ dst) {
  size_t i = (size_t)blockIdx.x * 256 + threadIdx.x;
  int c = (int)((i * 4) / NP);
  float s = sc[c], h = sh[c];
  float4 b4 = ((const float4*)base)[i];
  float4 r4 = ((const float4*)raw)[i];
  float4 o;
  o.x = b4.x + fmaf(r4.x, s, h); o.y = b4.y + fmaf(r4.y, s, h);
  o.z = b4.z + fmaf(r4.z, s, h); o.w = b4.w + fmaf(r4.w, s, h);
  ((float4*)dst)[i] = o;
}

// ---------------- edge scores + dst histogram ----------------------------------
__global__ __launch_bounds__(256) void k_edge(const int* __restrict__ info,
                                              const float* __restrict__ msk,
                                              const float* __restrict__ sig,
                                              float* __restrict__ aij,
                                              int* __restrict__ counts) {
  int e = blockIdx.x * 256 + threadIdx.x;
  int4 ii = ((const int4*)info)[e];   // src, k1, dst, k2
  float s = sig[(size_t)ii.y * NP + ii.x] + sig[(size_t)ii.w * NP + ii.z];
  s = fminf(fmaxf(s, -5.f), 5.f);
  aij[e] = expf(s) * msk[e];
  atomicAdd(&counts[ii.z], 1);
}

// ---------------- counting-sort by dst -----------------------------------------
__global__ __launch_bounds__(256) void k_scan1(const int* __restrict__ counts,
                                               int* __restrict__ offsets,
                                               int* __restrict__ bsum) {
  __shared__ int sm[256];
  int t = threadIdx.x;
  int i = blockIdx.x * 256 + t;
  int v = counts[i];
  sm[t] = v;
  __syncthreads();
  for (int d = 1; d < 256; d <<= 1) {
    int add = (t >= d) ? sm[t - d] : 0;
    __syncthreads();
    sm[t] += add;
    __syncthreads();
  }
  offsets[i] = sm[t] - v;
  if (t == 255) bsum[blockIdx.x] = sm[255];
}
__global__ __launch_bounds__(256) void k_scan2(const int* __restrict__ bsum,
                                               int* __restrict__ boff) {
  __shared__ int sm[256];
  int t = threadIdx.x;
  int v = (t < 144) ? bsum[t] : 0;
  sm[t] = v;
  __syncthreads();
  for (int d = 1; d < 256; d <<= 1) {
    int add = (t >= d) ? sm[t - d] : 0;
    __syncthreads();
    sm[t] += add;
    __syncthreads();
  }
  boff[t] = sm[t] - v;
}
__global__ __launch_bounds__(256) void k_scan3(int* __restrict__ offsets,
                                               const int* __restrict__ boff,
                                               int* __restrict__ cursor) {
  int i = blockIdx.x * 256 + threadIdx.x;
  int o = offsets[i] + boff[blockIdx.x];
  offsets[i] = o;
  cursor[i] = o;
  if (i == 0) offsets[NP] = EDGES;
}
__global__ __launch_bounds__(256) void k_scatter(const int* __restrict__ info,
                                                 int* __restrict__ cursor,
                                                 int* __restrict__ sorted) {
  int e = blockIdx.x * 256 + threadIdx.x;
  int d = info[4 * e + 2];
  int pos = atomicAdd(&cursor[d], 1);
  sorted[pos] = e;
}

// ---------------- per-node aggregation (one wave per node) ---------------------
__global__ __launch_bounds__(256) void k_agg(const int* __restrict__ offsets,
                                             const int* __restrict__ sorted,
                                             const float* __restrict__ aij,
                                             const int* __restrict__ info,
                                             const float* __restrict__ Xn,
                                             float* __restrict__ Xtr) {
  int wave = threadIdx.x >> 6, lane = threadIdx.x & 63;
  int node = blockIdx.x * 4 + wave;
  int o0 = offsets[node], o1 = offsets[node + 1];
  float ax = 0.f, ay = 0.f, az = 0.f, aw = 0.f, asum = 0.f;
  for (int i = o0; i < o1; i++) {
    int e = sorted[i];
    float a = aij[e];
    int s = info[4 * e];
    float4 v = ((const float4*)(Xn + (size_t)s * CH))[lane];
    ax = fmaf(a, v.x, ax); ay = fmaf(a, v.y, ay);
    az = fmaf(a, v.z, az); aw = fmaf(a, v.w, aw);
    asum += a;
  }
  float inv = 1.f / (asum + 1e-5f);
  float4 o = {ax * inv, ay * inv, az * inv, aw * inv};
  ((float4*)(Xtr + (size_t)node * CH))[lane] = o;
}

// ---------------- bn1d stats ----------------------------------------------------
__global__ __launch_bounds__(256) void k_colstats(const float* __restrict__ Xt,
                                                  float* __restrict__ sums,
                                                  float* __restrict__ sqs) {
  int c = threadIdx.x;
  float s = 0.f, q = 0.f;
  for (int n = blockIdx.x; n < NP; n += gridDim.x) {
    float v = Xt[(size_t)n * CH + c];
    s += v; q += v * v;
  }
  atomicAdd(&sums[c], s);
  atomicAdd(&sqs[c], q);
}
__global__ __launch_bounds__(256) void k_bn1dfin(const float* __restrict__ sums,
                                                 const float* __restrict__ sqs,
                                                 const float* __restrict__ g,
                                                 const float* __restrict__ b,
                                                 float* __restrict__ sct,
                                                 float* __restrict__ sht) {
  int c = threadIdx.x;
  float mean = sums[c] * (1.f / NP);
  float var = sqs[c] * (1.f / NP) - mean * mean;
  float iv = rsqrtf(var + BNEPS);
  float scl = g[c] * iv;
  sct[c] = scl;
  sht[c] = b[c] - mean * scl;
}

// ---------------- img4 = transpose(Xn + Xtr*sct+sht)  (N x C -> C x N) ---------
__global__ __launch_bounds__(256) void k_mkimg4(const float* __restrict__ Xn,
                                                const float* __restrict__ Xtr,
                                                const float* __restrict__ sct,
                                                const float* __restrict__ sht,
                                                float* __restrict__ img4) {
  __shared__ float tile[32][33];
  int c0 = blockIdx.x * 32, n0 = blockIdx.y * 32;
  int tx = threadIdx.x & 31, ty = threadIdx.x >> 5;
  int c = c0 + tx;
  float s = sct[c], h = sht[c];
#pragma unroll
  for (int j = 0; j < 4; j++) {
    size_t idx = (size_t)(n0 + ty + 8 * j) * CH + c;
    tile[ty + 8 * j][tx] = Xn[idx] + fmaf(Xtr[idx], s, h);
  }
  __syncthreads();
#pragma unroll
  for (int j = 0; j < 4; j++) {
    int cc = c0 + ty + 8 * j;
    img4[(size_t)cc * NP + n0 + tx] = tile[tx][ty + 8 * j];
  }
}

// ---------------- out(N x C) = transpose(raw5*sc5+sh5 + img4) ------------------
__global__ __launch_bounds__(256) void k_final(const float* __restrict__ raw5,
                                               const float* __restrict__ img4,
                                               const float* __restrict__ sc5,
                                               const float* __restrict__ sh5,
                                               float* __restrict__ out) {
  __shared__ float tile[32][33];
  int n0 = blockIdx.x * 32, c0 = blockIdx.y * 32;
  int tx = threadIdx.x & 31, ty = threadIdx.x >> 5;
#pragma unroll
  for (int j = 0; j < 4; j++) {
    int c = c0 + ty + 8 * j;
    size_t idx = (size_t)c * NP + n0 + tx;
    tile[ty + 8 * j][tx] = fmaf(raw5[idx], sc5[c], sh5[c]) + img4[idx];
  }
  __syncthreads();
#pragma unroll
  for (int j = 0; j < 4; j++) {
    int n = n0 + ty + 8 * j;
    out[(size_t)n * CH + c0 + tx] = tile[tx][ty + 8 * j];
  }
}

extern "C" void kernel_launch(void* const* d_in, const int* in_sizes, int n_in,
                              void* d_out, int out_size, void* d_ws, size_t ws_size,
                              hipStream_t stream) {
  (void)in_sizes; (void)n_in; (void)out_size; (void)ws_size;
  const float* X    = (const float*)d_in[0];
  const int*   info = (const int*)d_in[1];
  const float* msk  = (const float*)d_in[2];
  const float* pw0  = (const float*)d_in[3];
  const float* pg0  = (const float*)d_in[4];
  const float* pb0  = (const float*)d_in[5];
  const float* pw1  = (const float*)d_in[6];
  const float* pg1  = (const float*)d_in[7];
  const float* pb1  = (const float*)d_in[8];
  const float* f1w0 = (const float*)d_in[9];
  const float* f1g0 = (const float*)d_in[10];
  const float* f1b0 = (const float*)d_in[11];
  const float* f1w1 = (const float*)d_in[12];
  const float* f1g1 = (const float*)d_in[13];
  const float* f1b1 = (const float*)d_in[14];
  const float* dw1  = (const float*)d_in[15];
  const float* db1  = (const float*)d_in[16];
  const float* dw2  = (const float*)d_in[17];
  const float* db2  = (const float*)d_in[18];
  const float* bng  = (const float*)d_in[19];
  const float* bnb  = (const float*)d_in[20];
  const float* f2w0 = (const float*)d_in[21];
  const float* f2g0 = (const float*)d_in[22];
  const float* f2b0 = (const float*)d_in[23];
  const float* f2w1 = (const float*)d_in[24];
  const float* f2g1 = (const float*)d_in[25];
  const float* f2b1 = (const float*)d_in[26];
  float* out = (float*)d_out;

  float* ws = (float*)d_ws;
  // small scalars
  float* sc0 = ws + 0;    float* sh0 = ws + 256;
  float* sc1 = ws + 512;  float* sh1 = ws + 768;
  float* sc2 = ws + 1024; float* sh2 = ws + 1280;
  float* sc3 = ws + 1536; float* sh3 = ws + 1792;
  float* sc4 = ws + 2048; float* sh4 = ws + 3072;  // 1024 each
  float* sc5 = ws + 4096; float* sh5 = ws + 4352;
  float* sct = ws + 4608; float* sht = ws + 4864;
  float* sums = ws + 5120; float* sqs = ws + 5376;
  int* counts  = (int*)(ws + 8192);
  int* offsets = (int*)(ws + 45056);
  int* cursor  = (int*)(ws + 82176);
  int* bsum    = (int*)(ws + 119296);
  int* boff    = (int*)(ws + 119552);
  int* sorted  = (int*)(ws + 131072);
  float* aij   = ws + 425984;
  // big slots (physical order: D, B, A, C so A+C are adjacent for raw4bf)
  const size_t S = (size_t)NP * CH;        // 9437184 words
  float* slotD = ws + 720896;
  float* slotB = slotD + S;
  float* slotA = slotB + S;
  float* slotC = slotA + S;
  u16* bfB  = (u16*)(slotC + S);           // NP x 256 bf16
  u16* bfH  = bfB + S;                     // NP x 256 bf16
  float* sigT = (float*)(bfH + S);         // KSIG x NP fp32
  u16* bfW  = (u16*)(sigT + (size_t)KSIG * NP);
  u16* raw4bf  = (u16*)slotA;              // 1024 x NP bf16, spans slotA+slotC
  u16* bfT1024 = bfB;                      // NP x 1024 bf16, spans bfB+bfH+part sigT

  hipMemsetAsync(counts, 0, NP * sizeof(int), stream);
  hipMemsetAsync(sums, 0, 512 * sizeof(float), stream);

  dim3 b256(256);
  k_cvtW<<<2432, b256, 0, stream>>>(pw1, f1w0, f1w1, dw1, dw2, f2w1, bfW);
  // img = X^T
  k_transpose<<<dim3(CH / 32, NP / 32), b256, 0, stream>>>(X, slotA, NP, CH);
  // ppm
  k_dwconv17<<<dim3(36, CH), b256, 0, stream>>>(slotA, pw0, slotB);
  k_rowstats<<<CH, b256, 0, stream>>>(slotB, pg0, pb0, sc0, sh0);
  k_cvtT<<<dim3(NP / 64, CH / 32), b256, 0, stream>>>(slotB, bfB, sc0, sh0, CH, 2);
  k_mgemm<<<dim3(NP / 128, 2), b256, 0, stream>>>(bfW, bfB, slotC, nullptr, CH, CH, 0);
  k_rowstats<<<CH, b256, 0, stream>>>(slotC, pg1, pb1, sc1, sh1);
  k_addbn<<<NP * CH / 1024, b256, 0, stream>>>(slotA, slotC, sc1, sh1, slotD); // img2
  // ffn1
  k_cvtT<<<dim3(NP / 64, CH / 32), b256, 0, stream>>>(slotD, bfB, nullptr, nullptr, CH, 1);
  k_mgemm<<<dim3(NP / 128, 2), b256, 0, stream>>>(bfW + 65536, bfB, slotB, nullptr, CH, CH, 0);
  k_rowstats<<<CH, b256, 0, stream>>>(slotB, f1g0, f1b0, sc2, sh2);
  k_cvtT<<<dim3(NP / 64, CH / 32), b256, 0, stream>>>(slotB, bfB, sc2, sh2, CH, 2);
  k_mgemm<<<dim3(NP / 128, 2), b256, 0, stream>>>(bfW + 131072, bfB, slotC, nullptr, CH, CH, 0);
  k_rowstats<<<CH, b256, 0, stream>>>(slotC, f1g1, f1b1, sc3, sh3);
  k_addbn<<<NP * CH / 1024, b256, 0, stream>>>(slotD, slotC, sc3, sh3, slotA); // img3
  // Xn
  k_transpose<<<dim3(NP / 32, CH / 32), b256, 0, stream>>>(slotA, slotC, CH, NP); // Xn fp32
  k_cvtT<<<dim3(NP / 64, CH / 32), b256, 0, stream>>>(slotA, bfB, nullptr, nullptr, CH, 0);
  // dis
  k_mgemm<<<dim3(NP / 128, 2), b256, 0, stream>>>(bfW + 196608, bfB, slotB, db1, CH, CH, 1); // h
  k_cvtT<<<dim3(NP / 64, CH / 32), b256, 0, stream>>>(slotB, bfH, nullptr, nullptr, CH, 0);
  k_mgemm<<<dim3(NP / 128, 3), b256, 0, stream>>>(bfW + 262144, bfH, sigT, db2, CH, KSIG, 0);
  // edges
  k_edge<<<EDGES / 256, b256, 0, stream>>>(info, msk, sigT, aij, counts);
  k_scan1<<<NP / 256, b256, 0, stream>>>(counts, offsets, bsum);
  k_scan2<<<1, b256, 0, stream>>>(bsum, boff);
  k_scan3<<<NP / 256, b256, 0, stream>>>(offsets, boff, cursor);
  k_scatter<<<EDGES / 256, b256, 0, stream>>>(info, cursor, sorted);
  k_agg<<<NP / 4, b256, 0, stream>>>(offsets, sorted, aij, info, slotC, slotA); // Xtr
  k_colstats<<<288, b256, 0, stream>>>(slotA, sums, sqs);
  k_bn1dfin<<<1, b256, 0, stream>>>(sums, sqs, bng, bnb, sct, sht);
  k_mkimg4<<<dim3(CH / 32, NP / 32), b256, 0, stream>>>(slotC, slotA, sct, sht, slotD); // img4
  // ffn2
  k_conv3x4<<<dim3(36, CH), b256, 0, stream>>>(slotD, f2w0, raw4bf);
  k_rowstats_bf<<<4 * CH, b256, 0, stream>>>(raw4bf, f2g0, f2b0, sc4, sh4);
  k_cvtT_bf<<<dim3(NP / 64, 1024 / 32), b256, 0, stream>>>(raw4bf, bfT1024, sc4, sh4, 1024);
  k_mgemm<<<dim3(NP / 128, 2), b256, 0, stream>>>(bfW + 360448, bfT1024, slotB, nullptr, 1024, CH, 0);
  k_rowstats<<<CH, b256, 0, stream>>>(slotB, f2g1, f2b1, sc5, sh5);
  k_final<<<dim3(NP / 32, CH / 32), b256, 0, stream>>>(slotB, slotD, sc5, sh5, out);
}